// Round 7
// baseline (1556.535 us; speedup 1.0000x reference)
//
#include <hip/hip_runtime.h>
#include <stdint.h>

#define IN_F   512
#define OUT_F  512
#define BATCH  512
#define NWG    128
#define TPB    256
#define BAND   4   // NWG*BAND == OUT_F

#define SENT 0xFFFFFFFFu

__device__ __forceinline__ float4 ld4(const float* p) {
    return *reinterpret_cast<const float4*>(p);
}
__device__ __forceinline__ float clmp1(float v) {
    return fminf(1.0f, fmaxf(-1.0f, v));
}
__device__ __forceinline__ float wsum(float v) {
#pragma unroll
    for (int o = 32; o > 0; o >>= 1) v += __shfl_xor(v, o);
    return v;
}
__device__ __forceinline__ float wmaxr(float v) {
#pragma unroll
    for (int o = 32; o > 0; o >>= 1) v = fmaxf(v, __shfl_xor(v, o));
    return v;
}
__device__ __forceinline__ float wminr(float v) {
#pragma unroll
    for (int o = 32; o > 0; o >>= 1) v = fminf(v, __shfl_xor(v, o));
    return v;
}

// Publish protocol: slot(t,j) = msbuf[(t*NWG+j) << sshift] holds bits of
// u_j(t) = sum_{c in band j} exp(l_c(t)).  sshift=5 -> 128B stride: each
// publisher owns a PRIVATE cache line, so the 128 per-step publish stores
// acquire 128 distinct lines in parallel at the coherence point (the packed
// layout serialized 32 same-line ownership acquisitions -> ~2.4us gather).
// Max-free softmax is fp32-safe (logits O(0.3)); sentinel never produced.
// Payload rides inside the 4B word -> relaxed agent scope, no fences.
__global__ __launch_bounds__(TPB, 1) void plastic_scan_kernel(
    const float* __restrict__ x,      // [BATCH][IN_F]
    const float* __restrict__ eta,    // [BATCH][IN_F][OUT_F]
    const float* __restrict__ w,      // [IN_F][OUT_F]
    const float* __restrict__ alpha,  // [IN_F][OUT_F]
    float* __restrict__ out,          // [BATCH][OUT_F]
    unsigned int* __restrict__ msbuf, // [BATCH*NWG << sshift], sentinel 0xFF
    int sshift)
{
    __shared__ float wred[4][12];   // [wave][0..3]=A, [4..7]=B, [8..11]=hull
    __shared__ float wredL[4][4];   // honest-logit partials
    __shared__ __align__(16) float sXO[4];
    __shared__ unsigned int sFlag;

    const int tid = threadIdx.x;
    const int wv  = tid >> 6;
    const int pb  = blockIdx.x;
    const int j    = ((pb & 7) * (NWG / 8)) + (pb >> 3);  // XCD-banded remap
    const int col0 = j * BAND;
    const int r0 = tid;
    const int r1 = tid + TPB;

    const size_t estep = (size_t)IN_F * OUT_F;
    const float* ebase = eta + col0;

    // ---- persistent per-thread state (registers) ----
    float4 wA = ld4(&w[(size_t)r0 * OUT_F + col0]);
    float4 wB = ld4(&w[(size_t)r1 * OUT_F + col0]);
    float4 aA = ld4(&alpha[(size_t)r0 * OUT_F + col0]);
    float4 aB = ld4(&alpha[(size_t)r1 * OUT_F + col0]);
    float4 trA = make_float4(0.f, 0.f, 0.f, 0.f);
    float4 trB = make_float4(0.f, 0.f, 0.f, 0.f);

    float4 eA0 = ld4(ebase + 0 * estep + (size_t)r0 * OUT_F);
    float4 eB0 = ld4(ebase + 0 * estep + (size_t)r1 * OUT_F);
    float4 eA1 = ld4(ebase + 1 * estep + (size_t)r0 * OUT_F);
    float4 eB1 = ld4(ebase + 1 * estep + (size_t)r1 * OUT_F);
    float4 eA2 = ld4(ebase + 2 * estep + (size_t)r0 * OUT_F);
    float4 eB2 = ld4(ebase + 2 * estep + (size_t)r1 * OUT_F);
    float xPA = x[r0],            xPB = x[r1];
    float x1A = x[IN_F + r0],     x1B = x[IN_F + r1];
    float x2A = x[2 * IN_F + r0], x2B = x[2 * IN_F + r1];

    // lane0-resident published-logit state and folded linearization
    float e0 = 0, e1 = 0, e2 = 0, e3 = 0;
    float A0, A1, A2, A3, B0, B1, B2, B3, hBp, hSp, hBn, hSn;

    // ================= prologue =================
    // honest l(0) = x(0) @ w   (trace(0) = 0)
    {
        float p0 = xPA * wA.x + xPB * wB.x;
        float p1 = xPA * wA.y + xPB * wB.y;
        float p2 = xPA * wA.z + xPB * wB.z;
        float p3 = xPA * wA.w + xPB * wB.w;
        p0 = wsum(p0); p1 = wsum(p1); p2 = wsum(p2); p3 = wsum(p3);
        if ((tid & 63) == 0) {
            wredL[wv][0] = p0; wredL[wv][1] = p1;
            wredL[wv][2] = p2; wredL[wv][3] = p3;
        }
    }
    // A/B/hull for publish target t=1: base=0, slope=eta(0)*x(0)
    {
        float sA0 = eA0.x * xPA, sA1 = eA0.y * xPA, sA2 = eA0.z * xPA, sA3 = eA0.w * xPA;
        float sB0 = eB0.x * xPB, sB1 = eB0.y * xPB, sB2 = eB0.z * xPB, sB3 = eB0.w * xPB;
        float pA0 = x1A * wA.x + x1B * wB.x;
        float pA1 = x1A * wA.y + x1B * wB.y;
        float pA2 = x1A * wA.z + x1B * wB.z;
        float pA3 = x1A * wA.w + x1B * wB.w;
        float pB0 = x1A * (aA.x * sA0) + x1B * (aB.x * sB0);
        float pB1 = x1A * (aA.y * sA1) + x1B * (aB.y * sB1);
        float pB2 = x1A * (aA.z * sA2) + x1B * (aB.z * sB2);
        float pB3 = x1A * (aA.w * sA3) + x1B * (aB.w * sB3);
        float hsp = fmaxf(fmaxf(fmaxf(sA0, sA1), fmaxf(sA2, sA3)),
                          fmaxf(fmaxf(sB0, sB1), fmaxf(sB2, sB3)));
        hsp = fmaxf(hsp, 0.f);
        float hsn = fminf(fminf(fminf(sA0, sA1), fminf(sA2, sA3)),
                          fminf(fminf(sB0, sB1), fminf(sB2, sB3)));
        hsn = fminf(hsn, 0.f);
        pA0 = wsum(pA0); pA1 = wsum(pA1); pA2 = wsum(pA2); pA3 = wsum(pA3);
        pB0 = wsum(pB0); pB1 = wsum(pB1); pB2 = wsum(pB2); pB3 = wsum(pB3);
        hsp = wmaxr(hsp); hsn = wminr(hsn);
        if ((tid & 63) == 0) {
            float* wr = wred[wv];
            wr[0] = pA0; wr[1] = pA1; wr[2] = pA2; wr[3] = pA3;
            wr[4] = pB0; wr[5] = pB1; wr[6] = pB2; wr[7] = pB3;
            wr[8] = 0.f; wr[9] = hsp; wr[10] = 0.f; wr[11] = hsn;
        }
    }
    __syncthreads();
    if (tid == 0) {
        float l0 = wredL[0][0] + wredL[1][0] + wredL[2][0] + wredL[3][0];
        float l1 = wredL[0][1] + wredL[1][1] + wredL[2][1] + wredL[3][1];
        float l2 = wredL[0][2] + wredL[1][2] + wredL[2][2] + wredL[3][2];
        float l3 = wredL[0][3] + wredL[1][3] + wredL[2][3] + wredL[3][3];
        e0 = __expf(l0); e1 = __expf(l1); e2 = __expf(l2); e3 = __expf(l3);
        float u = (e0 + e1) + (e2 + e3);
        __hip_atomic_store(&msbuf[(size_t)j << sshift], __float_as_uint(u),
                           __ATOMIC_RELAXED, __HIP_MEMORY_SCOPE_AGENT);
    }

    // ================= steady loop =================
    for (int t = 0; t < BATCH; ++t) {
        // prefetch eta(t+3) and x(t+3) (hidden under the poll)
        float4 eA3, eB3;
        if (t + 3 < BATCH) {
            eA3 = ld4(ebase + (size_t)(t + 3) * estep + (size_t)r0 * OUT_F);
            eB3 = ld4(ebase + (size_t)(t + 3) * estep + (size_t)r1 * OUT_F);
        } else {
            eA3 = make_float4(0.f, 0.f, 0.f, 0.f);
            eB3 = make_float4(0.f, 0.f, 0.f, 0.f);
        }
        // lane0: fold shadow results (A/B/hull for publish target t+1)
        if (tid == 0) {
            A0 = wred[0][0] + wred[1][0] + wred[2][0] + wred[3][0];
            A1 = wred[0][1] + wred[1][1] + wred[2][1] + wred[3][1];
            A2 = wred[0][2] + wred[1][2] + wred[2][2] + wred[3][2];
            A3 = wred[0][3] + wred[1][3] + wred[2][3] + wred[3][3];
            B0 = wred[0][4] + wred[1][4] + wred[2][4] + wred[3][4];
            B1 = wred[0][5] + wred[1][5] + wred[2][5] + wred[3][5];
            B2 = wred[0][6] + wred[1][6] + wred[2][6] + wred[3][6];
            B3 = wred[0][7] + wred[1][7] + wred[2][7] + wred[3][7];
            hBp = fmaxf(fmaxf(wred[0][8], wred[1][8]), fmaxf(wred[2][8], wred[3][8]));
            hSp = fmaxf(fmaxf(wred[0][9], wred[1][9]), fmaxf(wred[2][9], wred[3][9]));
            hBn = fminf(fminf(wred[0][10], wred[1][10]), fminf(wred[2][10], wred[3][10]));
            hSn = fminf(fminf(wred[0][11], wred[1][11]), fminf(wred[2][11], wred[3][11]));
        }
        // ---- poll: 128 line-disjoint slots, lane L reads slots 2L, 2L+1 ----
        float S_tot = 0.f;
        if (tid < 64) {
            const unsigned int* pa0 =
                msbuf + (((size_t)t * NWG + 2 * tid) << sshift);
            const unsigned int* pa1 = pa0 + ((size_t)1 << sshift);
            unsigned int va, vb;
            for (;;) {
                asm volatile("global_load_dword %0, %2, off sc0 sc1\n\t"
                             "global_load_dword %1, %3, off sc0 sc1\n\t"
                             "s_waitcnt vmcnt(0)"
                             : "=v"(va), "=v"(vb) : "v"(pa0), "v"(pa1) : "memory");
                if (__all((va != SENT) & (vb != SENT))) break;
            }
            S_tot = wsum(__uint_as_float(va) + __uint_as_float(vb));
        }
        // ---- lane0: softmax of own band, immediate linearized publish ----
        if (tid == 0) {
            float rS = 1.0f / S_tot;
            float xo0 = e0 * rS, xo1 = e1 * rS, xo2 = e2 * rS, xo3 = e3 * rS;
            unsigned int flag = 1u;
            if (t < BATCH - 1) {
                float xom = fmaxf(fmaxf(xo0, xo1), fmaxf(xo2, xo3));
                bool ok = (hBp + hSp * xom <= 1.0f) && (hBn + hSn * xom >= -1.0f);
                if (ok) {
                    e0 = __expf(A0 + B0 * xo0); e1 = __expf(A1 + B1 * xo1);
                    e2 = __expf(A2 + B2 * xo2); e3 = __expf(A3 + B3 * xo3);
                    float u = (e0 + e1) + (e2 + e3);
                    __hip_atomic_store(&msbuf[((size_t)(t + 1) * NWG + j) << sshift],
                                       __float_as_uint(u),
                                       __ATOMIC_RELAXED, __HIP_MEMORY_SCOPE_AGENT);
                } else {
                    flag = 0u;  // defer: honest publish after real trace update
                }
            }
            sXO[0] = xo0; sXO[1] = xo1; sXO[2] = xo2; sXO[3] = xo3;
            sFlag = flag;
            *(float4*)&out[(size_t)t * OUT_F + col0] = make_float4(xo0, xo1, xo2, xo3);
        }
        __syncthreads();
        if (t == BATCH - 1) break;

        const unsigned int flag = sFlag;
        const float xo0 = sXO[0], xo1 = sXO[1], xo2 = sXO[2], xo3 = sXO[3];

        // ---- trace(t+1) = clip((1-eta(t))*tr + eta(t)*x(t)*xo(t)) ----
        trA.x = clmp1((1.f - eA0.x) * trA.x + eA0.x * (xPA * xo0));
        trA.y = clmp1((1.f - eA0.y) * trA.y + eA0.y * (xPA * xo1));
        trA.z = clmp1((1.f - eA0.z) * trA.z + eA0.z * (xPA * xo2));
        trA.w = clmp1((1.f - eA0.w) * trA.w + eA0.w * (xPA * xo3));
        trB.x = clmp1((1.f - eB0.x) * trB.x + eB0.x * (xPB * xo0));
        trB.y = clmp1((1.f - eB0.y) * trB.y + eB0.y * (xPB * xo1));
        trB.z = clmp1((1.f - eB0.z) * trB.z + eB0.z * (xPB * xo2));
        trB.w = clmp1((1.f - eB0.w) * trB.w + eB0.w * (xPB * xo3));

        if (!flag) {  // uniform branch — rare/never
            float p0 = x1A * (wA.x + aA.x * trA.x) + x1B * (wB.x + aB.x * trB.x);
            float p1 = x1A * (wA.y + aA.y * trA.y) + x1B * (wB.y + aB.y * trB.y);
            float p2 = x1A * (wA.z + aA.z * trA.z) + x1B * (wB.z + aB.z * trB.z);
            float p3 = x1A * (wA.w + aA.w * trA.w) + x1B * (wB.w + aB.w * trB.w);
            p0 = wsum(p0); p1 = wsum(p1); p2 = wsum(p2); p3 = wsum(p3);
            if ((tid & 63) == 0) {
                wredL[wv][0] = p0; wredL[wv][1] = p1;
                wredL[wv][2] = p2; wredL[wv][3] = p3;
            }
            __syncthreads();
            if (tid == 0) {
                float l0 = wredL[0][0] + wredL[1][0] + wredL[2][0] + wredL[3][0];
                float l1 = wredL[0][1] + wredL[1][1] + wredL[2][1] + wredL[3][1];
                float l2 = wredL[0][2] + wredL[1][2] + wredL[2][2] + wredL[3][2];
                float l3 = wredL[0][3] + wredL[1][3] + wredL[2][3] + wredL[3][3];
                e0 = __expf(l0); e1 = __expf(l1); e2 = __expf(l2); e3 = __expf(l3);
                float u = (e0 + e1) + (e2 + e3);
                __hip_atomic_store(&msbuf[((size_t)(t + 1) * NWG + j) << sshift],
                                   __float_as_uint(u),
                                   __ATOMIC_RELAXED, __HIP_MEMORY_SCOPE_AGENT);
            }
        }

        // ---- shadow: A/B/hull for publish target t+2 ----
        if (t <= BATCH - 3) {
            float bA0 = (1.f - eA1.x) * trA.x, bA1 = (1.f - eA1.y) * trA.y;
            float bA2 = (1.f - eA1.z) * trA.z, bA3 = (1.f - eA1.w) * trA.w;
            float bB0 = (1.f - eB1.x) * trB.x, bB1 = (1.f - eB1.y) * trB.y;
            float bB2 = (1.f - eB1.z) * trB.z, bB3 = (1.f - eB1.w) * trB.w;
            float sA0 = eA1.x * x1A, sA1 = eA1.y * x1A, sA2 = eA1.z * x1A, sA3 = eA1.w * x1A;
            float sB0 = eB1.x * x1B, sB1 = eB1.y * x1B, sB2 = eB1.z * x1B, sB3 = eB1.w * x1B;
            float pA0 = x2A * (wA.x + aA.x * bA0) + x2B * (wB.x + aB.x * bB0);
            float pA1 = x2A * (wA.y + aA.y * bA1) + x2B * (wB.y + aB.y * bB1);
            float pA2 = x2A * (wA.z + aA.z * bA2) + x2B * (wB.z + aB.z * bB2);
            float pA3 = x2A * (wA.w + aA.w * bA3) + x2B * (wB.w + aB.w * bB3);
            float pB0 = x2A * (aA.x * sA0) + x2B * (aB.x * sB0);
            float pB1 = x2A * (aA.y * sA1) + x2B * (aB.y * sB1);
            float pB2 = x2A * (aA.z * sA2) + x2B * (aB.z * sB2);
            float pB3 = x2A * (aA.w * sA3) + x2B * (aB.w * sB3);
            float hbp = fmaxf(fmaxf(fmaxf(bA0, bA1), fmaxf(bA2, bA3)),
                              fmaxf(fmaxf(bB0, bB1), fmaxf(bB2, bB3)));
            float hbn = fminf(fminf(fminf(bA0, bA1), fminf(bA2, bA3)),
                              fminf(fminf(bB0, bB1), fminf(bB2, bB3)));
            float hsp = fmaxf(fmaxf(fmaxf(sA0, sA1), fmaxf(sA2, sA3)),
                              fmaxf(fmaxf(sB0, sB1), fmaxf(sB2, sB3)));
            hsp = fmaxf(hsp, 0.f);
            float hsn = fminf(fminf(fminf(sA0, sA1), fminf(sA2, sA3)),
                              fminf(fminf(sB0, sB1), fminf(sB2, sB3)));
            hsn = fminf(hsn, 0.f);
            pA0 = wsum(pA0); pA1 = wsum(pA1); pA2 = wsum(pA2); pA3 = wsum(pA3);
            pB0 = wsum(pB0); pB1 = wsum(pB1); pB2 = wsum(pB2); pB3 = wsum(pB3);
            hbp = wmaxr(hbp); hsp = wmaxr(hsp);
            hbn = wminr(hbn); hsn = wminr(hsn);
            if ((tid & 63) == 0) {
                float* wr = wred[wv];
                wr[0] = pA0; wr[1] = pA1; wr[2] = pA2; wr[3] = pA3;
                wr[4] = pB0; wr[5] = pB1; wr[6] = pB2; wr[7] = pB3;
                wr[8] = hbp; wr[9] = hsp; wr[10] = hbn; wr[11] = hsn;
            }
        }

        // rotate rings
        eA0 = eA1; eB0 = eB1; eA1 = eA2; eB1 = eB2; eA2 = eA3; eB2 = eB3;
        xPA = x1A; xPB = x1B; x1A = x2A; x1B = x2B;
        if (t + 3 < BATCH) {
            x2A = x[(size_t)(t + 3) * IN_F + r0];
            x2B = x[(size_t)(t + 3) * IN_F + r1];
        }
        __syncthreads();  // wred/sXO ready for next iteration
    }
}

extern "C" void kernel_launch(void* const* d_in, const int* in_sizes, int n_in,
                              void* d_out, int out_size, void* d_ws, size_t ws_size,
                              hipStream_t stream) {
    const float* x     = (const float*)d_in[0];
    const float* eta   = (const float*)d_in[1];
    const float* w     = (const float*)d_in[2];
    // d_in[3] = b: scalar added to all logits -> cancels in softmax, unused
    const float* alpha = (const float*)d_in[4];
    float* out = (float*)d_out;
    unsigned int* msbuf = (unsigned int*)d_ws;

    // slot stride 1<<sshift dwords; sshift=5 -> 128B (one cache line per
    // publisher). Fall back to smaller stride if workspace is short.
    int sshift = 5;
    while (sshift > 0 &&
           (((size_t)BATCH * NWG * sizeof(unsigned int)) << sshift) > ws_size)
        --sshift;

    hipMemsetAsync(d_ws, 0xFF,
                   ((size_t)BATCH * NWG * sizeof(unsigned int)) << sshift, stream);

    plastic_scan_kernel<<<dim3(NWG), dim3(TPB), 0, stream>>>(
        x, eta, w, alpha, out, msbuf, sshift);
}